// Round 5
// baseline (251.480 us; speedup 1.0000x reference)
//
#include <hip/hip_runtime.h>
#include <hip/hip_bf16.h>
#include <math.h>

#define S_LEN 2048
#define DIN   2048
#define NH    32
#define NKV   8
#define HD    64
#define DOUT  2048        // NH*HD
#define QKVN  3072        // DOUT + 2*KVD
#define KOFF  2048        // k col offset in qkv
#define VOFF  2560        // v col offset in qkv

typedef __attribute__((ext_vector_type(8))) short short8v;    // 8 bf16 (4 VGPRs)
typedef __attribute__((ext_vector_type(8))) unsigned short ushort8v;
typedef __attribute__((ext_vector_type(4))) unsigned short ushort4v;
typedef __attribute__((ext_vector_type(4))) float float4v;
typedef __attribute__((ext_vector_type(16))) float float16v;

__device__ __forceinline__ float bf2f(unsigned short u) {
    union { float f; unsigned u; } c; c.u = ((unsigned)u) << 16; return c.f;
}
__device__ __forceinline__ unsigned short f2bf(float f) {
    union { float f; unsigned u; } c; c.f = f;
    unsigned r = c.u + 0x7fffu + ((c.u >> 16) & 1u);   // RNE
    return (unsigned short)(r >> 16);
}
__device__ __forceinline__ unsigned short f2h(float f) {
    union { _Float16 h; unsigned short u; } c; c.h = (_Float16)f; return c.u;
}
__device__ __forceinline__ float h2f(unsigned short u) {
    union { _Float16 h; unsigned short u; } c; c.u = u; return (float)c.h;
}
__device__ __forceinline__ unsigned cvtpk(float lo, float hi) {
    unsigned r;
    asm("v_cvt_pk_bf16_f32 %0, %1, %2" : "=v"(r) : "v"(lo), "v"(hi));
    return r;
}
__device__ __forceinline__ float fexp2(float x) {           // guaranteed 1 trans op
    float r;
    asm("v_exp_f32 %0, %1" : "=v"(r) : "v"(x));
    return r;
}

// ---------------------------------------------------------------------------
// Fused preprocessing, ONE launch, grid sections:
//   [0, 6144)        : Wq|Wk|Wv fp32 [K][N] -> bf16 [N][K] into W1 (32x32 tiles)
//   [6144, 10240)    : Wo transpose into WoT
//   [10240, 14336)   : x fp32 -> bf16 cast into XB
// ---------------------------------------------------------------------------
__global__ __launch_bounds__(256) void prep(const float* __restrict__ Wq,
                                            const float* __restrict__ Wk,
                                            const float* __restrict__ Wv,
                                            const float* __restrict__ Wo,
                                            const float* __restrict__ x,
                                            unsigned short* __restrict__ W1,
                                            unsigned short* __restrict__ WoT,
                                            unsigned short* __restrict__ XB) {
    __shared__ float t[32][33];
    const int a = blockIdx.x;
    const int tx = threadIdx.x & 31, ty = threadIdx.x >> 5;
    if (a < 6144) {                       // qkv weights: grid (96, 64)
        const int n0 = (a % 96) * 32, k0 = (a / 96) * 32;
        const float* src; int nn0, Nsrc;
        if (n0 < KOFF)      { src = Wq; nn0 = n0;        Nsrc = DOUT; }
        else if (n0 < VOFF) { src = Wk; nn0 = n0 - KOFF; Nsrc = 512; }
        else                { src = Wv; nn0 = n0 - VOFF; Nsrc = 512; }
#pragma unroll
        for (int j = ty; j < 32; j += 8)
            t[j][tx] = src[(size_t)(k0 + j) * Nsrc + nn0 + tx];
        __syncthreads();
#pragma unroll
        for (int j = ty; j < 32; j += 8)
            W1[(size_t)(n0 + j) * DIN + k0 + tx] = f2bf(t[tx][j]);
    } else if (a < 10240) {               // Wo: grid (64, 64), K=DOUT rows, N=DIN
        const int b = a - 6144;
        const int n0 = (b % 64) * 32, k0 = (b / 64) * 32;
#pragma unroll
        for (int j = ty; j < 32; j += 8)
            t[j][tx] = Wo[(size_t)(k0 + j) * DIN + n0 + tx];
        __syncthreads();
#pragma unroll
        for (int j = ty; j < 32; j += 8)
            WoT[(size_t)(n0 + j) * DOUT + k0 + tx] = f2bf(t[tx][j]);
    } else {                              // x cast: 4096 blocks x 1024 elems
        const int i = (a - 10240) * 1024 + threadIdx.x * 4;
        float4 v = *(const float4*)(x + i);
        XB[i + 0] = f2bf(v.x); XB[i + 1] = f2bf(v.y);
        XB[i + 2] = f2bf(v.z); XB[i + 3] = f2bf(v.w);
    }
}

// ---------------------------------------------------------------------------
// bf16 MFMA GEMM v2: 128x64 tile, BK=64, 4 waves stacked in M (wave = 32x64).
//   * Double-buffered LDS + counted vmcnt (T3/T4): prefetch in flight across
//     the barrier. T2 XOR swizzle via pre-swizzled global source. setprio(1)
//     around MFMA cluster.
// FUSE=1: bf16 out + per-head RMSNorm+RoPE epilogue (block col = one head).
// FUSE=0: fp32 out, plain.
// ---------------------------------------------------------------------------
template <int FUSE>
__global__ __launch_bounds__(256) void gemm64(const unsigned short* __restrict__ A,
                                              const unsigned short* __restrict__ Bt,
                                              void* __restrict__ Cv, int M, int N, int K,
                                              const float* __restrict__ qnw,
                                              const float* __restrict__ knw,
                                              const float* __restrict__ cosb,
                                              const float* __restrict__ sinb) {
    __shared__ __attribute__((aligned(16))) unsigned short As[2 * 128 * 64];
    __shared__ __attribute__((aligned(16))) unsigned short Bs[2 * 64 * 64];
    const int tid = threadIdx.x, lane = tid & 63, w = tid >> 6;
    const int bm = blockIdx.y * 128, bn = blockIdx.x * 64;
    const int wm = w * 32;

    float4v acc[2][4];
#pragma unroll
    for (int i = 0; i < 2; i++)
#pragma unroll
        for (int j = 0; j < 4; j++) acc[i][j] = (float4v){0.f, 0.f, 0.f, 0.f};

    const int srow = lane >> 3;
    const int schk = (lane & 7) ^ srow;
    const unsigned short* Ag[4];
    const unsigned short* Bg[2];
#pragma unroll
    for (int g = 0; g < 4; g++)
        Ag[g] = A + (size_t)(bm + w * 32 + g * 8 + srow) * K + schk * 8;
#pragma unroll
    for (int g = 0; g < 2; g++)
        Bg[g] = Bt + (size_t)(bn + w * 16 + g * 8 + srow) * K + schk * 8;

    auto STAGE = [&](int t, int b) {
        const size_t ko = (size_t)t * 64;
        unsigned short* Ad = As + b * (128 * 64) + (w * 32) * 64;
        unsigned short* Bd = Bs + b * (64 * 64) + (w * 16) * 64;
#pragma unroll
        for (int g = 0; g < 4; g++)
            __builtin_amdgcn_global_load_lds(
                (const __attribute__((address_space(1))) void*)(Ag[g] + ko),
                (__attribute__((address_space(3))) void*)(Ad + g * 8 * 64), 16, 0, 0);
#pragma unroll
        for (int g = 0; g < 2; g++)
            __builtin_amdgcn_global_load_lds(
                (const __attribute__((address_space(1))) void*)(Bg[g] + ko),
                (__attribute__((address_space(3))) void*)(Bd + g * 8 * 64), 16, 0, 0);
    };

    const int frow = lane & 15, quad = lane >> 4, sw = frow & 7;
    const int NT = K >> 6;

    STAGE(0, 0);                                   // prologue: tile 0 -> buf 0

    for (int t = 0; t < NT; t++) {
        const int c = t & 1;
        if (t + 1 < NT) {
            STAGE(t + 1, c ^ 1);
            asm volatile("s_waitcnt vmcnt(6)" ::: "memory");   // tile t done
        } else {
            asm volatile("s_waitcnt vmcnt(0)" ::: "memory");
        }
        __builtin_amdgcn_s_barrier();
        __builtin_amdgcn_sched_barrier(0);

        const unsigned short* Ab = As + c * (128 * 64);
        const unsigned short* Bb = Bs + c * (64 * 64);
        short8v af[2][2], bf[4][2];
#pragma unroll
        for (int fm = 0; fm < 2; fm++)
#pragma unroll
            for (int ks = 0; ks < 2; ks++)
                af[fm][ks] = *(const short8v*)(Ab + (wm + fm * 16 + frow) * 64 +
                                               (((ks * 4 + quad) ^ sw) * 8));
#pragma unroll
        for (int fn = 0; fn < 4; fn++)
#pragma unroll
            for (int ks = 0; ks < 2; ks++)
                bf[fn][ks] = *(const short8v*)(Bb + (fn * 16 + frow) * 64 +
                                               (((ks * 4 + quad) ^ sw) * 8));
        __builtin_amdgcn_s_setprio(1);
#pragma unroll
        for (int ks = 0; ks < 2; ks++)
#pragma unroll
            for (int fm = 0; fm < 2; fm++)
#pragma unroll
                for (int fn = 0; fn < 4; fn++)
                    acc[fm][fn] = __builtin_amdgcn_mfma_f32_16x16x32_bf16(
                        af[fm][ks], bf[fn][ks], acc[fm][fn], 0, 0, 0);
        __builtin_amdgcn_s_setprio(0);

        if (t + 1 < NT) {
            asm volatile("s_waitcnt lgkmcnt(0)" ::: "memory");  // reads pulled
            __builtin_amdgcn_sched_barrier(0);
            __builtin_amdgcn_s_barrier();          // buf c free to overwrite
        }
    }

    const int quad4 = lane >> 4, col16 = lane & 15;
    if constexpr (FUSE == 1) {
        unsigned short* C = (unsigned short*)Cv;
        const int head = bn >> 6;                 // one head per block col
        if (head < 40) {
            const float* nw = (head < 32) ? qnw : knw;
            float wv[4];
#pragma unroll
            for (int fn = 0; fn < 4; fn++) wv[fn] = nw[fn * 16 + col16];
#pragma unroll
            for (int fm = 0; fm < 2; fm++)
#pragma unroll
                for (int r = 0; r < 4; r++) {
                    float x0 = acc[fm][0][r], x1 = acc[fm][1][r];
                    float x2 = acc[fm][2][r], x3 = acc[fm][3][r];
                    float ss = x0 * x0 + x1 * x1 + x2 * x2 + x3 * x3;
                    ss += __shfl_xor(ss, 1); ss += __shfl_xor(ss, 2);
                    ss += __shfl_xor(ss, 4); ss += __shfl_xor(ss, 8);
                    const float inv = rsqrtf(ss * (1.0f / 64.0f) + 1e-6f);
                    float xn[4] = {x0 * inv * wv[0], x1 * inv * wv[1],
                                   x2 * inv * wv[2], x3 * inv * wv[3]};
                    const int row = bm + wm + fm * 16 + quad4 * 4 + r;
                    const float* cr = cosb + (size_t)row * HD;
                    const float* sr = sinb + (size_t)row * HD;
#pragma unroll
                    for (int fn = 0; fn < 4; fn++) {
                        const float rot = (fn < 2) ? -xn[fn + 2] : xn[fn - 2];
                        const float res = xn[fn] * cr[fn * 16 + col16] +
                                          rot * sr[fn * 16 + col16];
                        C[(size_t)row * N + bn + fn * 16 + col16] = f2bf(res);
                    }
                }
        } else {
#pragma unroll
            for (int fm = 0; fm < 2; fm++)
#pragma unroll
                for (int fn = 0; fn < 4; fn++)
#pragma unroll
                    for (int r = 0; r < 4; r++)
                        C[(size_t)(bm + wm + fm * 16 + quad4 * 4 + r) * N +
                          bn + fn * 16 + col16] = f2bf(acc[fm][fn][r]);
        }
    } else {
        float* C = (float*)Cv;
#pragma unroll
        for (int fm = 0; fm < 2; fm++)
#pragma unroll
            for (int fn = 0; fn < 4; fn++)
#pragma unroll
                for (int r = 0; r < 4; r++)
                    C[(size_t)(bm + wm + fm * 16 + quad4 * 4 + r) * N +
                      bn + fn * 16 + col16] = acc[fm][fn][r];
    }
}

// ---------------------------------------------------------------------------
// MFMA flash attention v8 (causal, GQA), fixed-max softmax.
//   * Swapped QK^T (mfma(K, Q), 32x32x16), lane-local softmax, in-register
//     P->bf16 (cvt_pk) + v_permlane32_swap_b32 redistribution. Lacc on the
//     matrix pipe. Double-buffered K/V LDS, one barrier/tile, 2-deep reg
//     prefetch.
//   * v8: 4 chunks per qtile-pair (33 = 9+8+8+8) -> 1024 blocks = 4/CU =
//     16 waves/CU (was 3/CU). KSTR 88->72 shrinks LDS to 36864 B/block
//     (4 x 36.9 KB = 147 KB <= 160 KB); launch_bounds(256,4).
//   * Partials: A0,A1 (qa rows <1024, chunks 0,1) + B0,B1,B2 (chunks 0-2)
//     fill the dead W1+XB overlay exactly (5 x 4.19 MB). B3 + all L slots
//     live in d_out (dead until out-proj; combine runs first).
// ---------------------------------------------------------------------------
#define KSTR 72    // K/V LDS row stride (shorts); 2*2*64*72*2B = 36864 B

__global__ __launch_bounds__(256, 4) void flash_part(const unsigned short* __restrict__ qb,
                                                     const unsigned short* __restrict__ kb,
                                                     const unsigned short* __restrict__ vb,
                                                     unsigned short* __restrict__ OpW,
                                                     unsigned short* __restrict__ OpD,
                                                     float* __restrict__ Lp) {
    __shared__ __attribute__((aligned(16))) unsigned short Ks[2][64 * KSTR];
    __shared__ __attribute__((aligned(16))) unsigned short Vt[2][64 * KSTR];

    const int tid = threadIdx.x, lane = tid & 63, w = tid >> 6;
    const int sl = lane & 31, hi = lane >> 5, hi8 = hi * 8;
    const int bid = blockIdx.x;
    const int g = bid & 7;                    // kv head
    const int p = (bid >> 3) & 31;            // pair index: qtiles p and 63-p
    const int c = bid >> 8;                   // chunk 0..3
    const int h = g * 4 + w;

    const int co   = c ? (9 + (c - 1) * 8) : 0;   // chunk offsets {0,9,17,25}
    const int clen = c ? 8 : 9;                   // chunk lengths {9,8,8,8}

    const int s0a = p * 32, s0b = (63 - p) * 32;
    const int nta = (s0a + 95) >> 6;          // 1..16 (qa tiles; qb = 33-nta)
    int nA = nta - co;                        // qa tiles in this window
    nA = nA < 0 ? 0 : (nA > clen ? clen : nA);

    const float C1 = 0.18033688011112042f;    // 0.125 * log2(e)
    const float C2 = 12.262908856239697f;     // 8.5  * log2(e)

    // partial slots: A_c (c<2) rows [0,1024); B_c rows [1024,2048)
    unsigned short* OhA = OpW + (size_t)c * 1024 * DOUT;
    float*          LhA = Lp + (size_t)c * 1024 * NH;
    unsigned short* OhB = (c < 3) ? (OpW + (size_t)(2 + c) * 1024 * DOUT) : OpD;
    float*          LhB = Lp + (size_t)(2 + c) * 1024 * NH;

    int seg = (c < 2) ? 0 : 1;                // chunks 2,3 are all-qb
    int s0 = seg == 0 ? s0a : s0b;

    // Q fragments (B-operand layout): lane holds Q[s0+sl][16*ksq + 8*hi + j]
    short8v qf[4];
#pragma unroll
    for (int ksq = 0; ksq < 4; ksq++)
        qf[ksq] = *(const short8v*)(qb + (size_t)(s0 + sl) * QKVN + h * HD +
                                    ksq * 16 + hi8);

    float16v O[2], Lacc;
#pragma unroll
    for (int df = 0; df < 2; df++)
#pragma unroll
        for (int r = 0; r < 16; r++) O[df][r] = 0.f;
#pragma unroll
    for (int r = 0; r < 16; r++) Lacc[r] = 0.f;

    short8v ones;
#pragma unroll
    for (int i = 0; i < 8; i++) ones[i] = (short)0x3F80;   // bf16 1.0

    // staging addresses
    const int kkey = tid >> 2, kch = tid & 3;     // K: 4 threads/key, 16 shorts
    const unsigned short* kg = kb + (size_t)kkey * QKVN + g * HD + kch * 16;
    const int kp = tid & 31, vdbb = tid >> 5;     // V: keys 2kp,2kp+1; dims vdbb*8..+8
    const unsigned short* vg0 = vb + (size_t)(2 * kp) * QKVN + g * HD + vdbb * 8;
    const unsigned short* vg1 = vg0 + QKVN;

    auto epi = [&](int sbase, unsigned short* Os, float* Ls, int roff) {
#pragma unroll
        for (int df = 0; df < 2; df++)
#pragma unroll
            for (int r = 0; r < 16; r++) {
                const int row = sbase + (r & 3) + 8 * (r >> 2) + 4 * hi - roff;
                Os[(size_t)row * DOUT + h * HD + df * 32 + sl] = f2h(O[df][r]);
            }
        if (sl == 0) {
#pragma unroll
            for (int r = 0; r < 16; r++) {
                const int row = sbase + (r & 3) + 8 * (r >> 2) + 4 * hi - roff;
                Ls[(size_t)row * NH + h] = Lacc[r];
            }
        }
    };
    auto zacc = [&]() {
#pragma unroll
        for (int df = 0; df < 2; df++)
#pragma unroll
            for (int r = 0; r < 16; r++) O[df][r] = 0.f;
#pragma unroll
        for (int r = 0; r < 16; r++) Lacc[r] = 0.f;
    };

    auto kt = [&](int jj) {                   // key-tile index for stream pos jj
        const int sj = co + jj;
        return (sj < nta) ? sj : (sj - nta);
    };

    ushort8v ka0, ka1, va0, va1;
    auto LOADREGS = [&](int it) {
        const size_t off = (size_t)it * 64 * QKVN;
        ka0 = *(const ushort8v*)(kg + off);
        ka1 = *(const ushort8v*)(kg + off + 8);
        va0 = *(const ushort8v*)(vg0 + off);
        va1 = *(const ushort8v*)(vg1 + off);
    };
    auto COMMIT = [&](int b) {
        unsigned short* kd = Ks[b] + kkey * KSTR + kch * 16;
        *(ushort8v*)kd = ka0;
        *(ushort8v*)(kd + 8) = ka1;
        union { ushort8v v; unsigned d[4]; } ua, ub;
        ua.v = va0; ub.v = va1;
        unsigned short* vd = Vt[b] + (size_t)(vdbb * 8) * KSTR + 2 * kp;
#pragma unroll
        for (int i = 0; i < 8; i++) {
            const unsigned sel = (i & 1) ? 0x07060302u : 0x05040100u;
            const unsigned word = __builtin_amdgcn_perm(ub.d[i >> 1], ua.d[i >> 1], sel);
            *(unsigned*)(vd + (size_t)i * KSTR) = word;
        }
    };

    // prologue: tile0 -> regs -> buf0; tile1 -> regs
    LOADREGS(kt(0));
    COMMIT(0);
    LOADREGS(kt(1));

#pragma unroll 1
    for (int jj = 0; jj < clen; jj++) {
        const int cur = jj & 1;
        __syncthreads();                    // buf[cur] committed; prev reads done
        if (jj + 1 < clen) COMMIT(cur ^ 1); // regs hold tile jj+1
        if (jj + 2 < clen) LOADREGS(kt(jj + 2));
        if (seg == 0 && jj == nA) {         // qa -> qb boundary (flush A partial)
            epi(s0a, OhA, LhA, 0);
            zacc();
            s0 = s0b; seg = 1;
#pragma unroll
            for (int ksq = 0; ksq < 4; ksq++)
                qf[ksq] = *(const short8v*)(qb + (size_t)(s0b + sl) * QKVN +
                                            h * HD + ksq * 16 + hi8);
        }

        const int t0 = kt(jj) * 64;
        const bool edge = (t0 + 63 > s0);

#pragma unroll
        for (int b = 0; b < 2; b++) {
            short8v kf[4];
#pragma unroll
            for (int ksq = 0; ksq < 4; ksq++)
                kf[ksq] = *(const short8v*)(Ks[cur] + (32 * b + sl) * KSTR +
                                            ksq * 16 + hi8);
            float16v sct;
#pragma unroll
            for (int r = 0; r < 16; r++) sct[r] = 0.f;
            __builtin_amdgcn_s_setprio(1);
#pragma unroll
            for (int ksq = 0; ksq < 4; ksq++)
                sct = __builtin_amdgcn_mfma_f32_32x32x16_bf16(kf[ksq], qf[ksq],
                                                              sct, 0, 0, 0);
            __builtin_amdgcn_s_setprio(0);
#pragma unroll
            for (int r = 0; r < 16; r++) {
                float arg = sct[r] * C1 - C2;
                if (edge) {
                    const int kglob = t0 + 32 * b + (r & 3) + 8 * (r >> 2) + 4 * hi;
                    arg = (kglob <= s0 + sl) ? arg : -100.f;
                }
                sct[r] = fexp2(arg);
            }
            unsigned pk[8];
#pragma unroll
            for (int i = 0; i < 8; i++) pk[i] = cvtpk(sct[2 * i], sct[2 * i + 1]);
#pragma unroll
            for (int kk = 0; kk < 2; kk++) {
                unsigned x0 = pk[4 * kk + 0], x1 = pk[4 * kk + 1];
                unsigned y0 = pk[4 * kk + 2], y1 = pk[4 * kk + 3];
                // halves swap: x' = {x_lo, y_lo}, y' = {x_hi, y_hi}
                asm("v_permlane32_swap_b32 %0, %1" : "+v"(x0), "+v"(y0));
                asm("v_permlane32_swap_b32 %0, %1" : "+v"(x1), "+v"(y1));
                union { unsigned u[4]; short8v v; } pa;
                pa.u[0] = x0; pa.u[1] = x1; pa.u[2] = y0; pa.u[3] = y1;
                const int ks = 2 * b + kk;
                __builtin_amdgcn_s_setprio(1);
#pragma unroll
                for (int df = 0; df < 2; df++) {
                    const short8v vf = *(const short8v*)(Vt[cur] +
                                                         (size_t)(df * 32 + sl) * KSTR +
                                                         ks * 16 + hi8);
                    O[df] = __builtin_amdgcn_mfma_f32_32x32x16_bf16(pa.v, vf,
                                                                    O[df], 0, 0, 0);
                }
                Lacc = __builtin_amdgcn_mfma_f32_32x32x16_bf16(pa.v, ones,
                                                               Lacc, 0, 0, 0);
                __builtin_amdgcn_s_setprio(0);
            }
        }
    }

    if (seg == 0) {            // window was all-qa: flush A, B partial = zeros
        epi(s0a, OhA, LhA, 0);
        zacc();
    }
    epi(s0b, OhB, LhB, 1024);  // every block writes its B partial
}

// ---------------------------------------------------------------------------
// Combine: rows < 1024 merge A0+A1; rows >= 1024 merge B0+B1+B2+B3.
// ctx (bf16) written to CTX (the dead QKV region).
// ---------------------------------------------------------------------------
__global__ __launch_bounds__(256) void combine(const unsigned short* __restrict__ OpW,
                                               const unsigned short* __restrict__ OpD,
                                               const float* __restrict__ Lp,
                                               unsigned short* __restrict__ CTX) {
    const int i4 = (blockIdx.x * 256 + threadIdx.x) * 4;
    const int row = i4 >> 11, hh = (i4 & 2047) >> 6;
    float acc[4];
    float l;
    if (row < 1024) {          // wave-uniform (block spans half a row)
        ushort4v a0 = *(const ushort4v*)(OpW + i4);
        ushort4v a1 = *(const ushort4v*)(OpW + (size_t)1024 * DOUT + i4);
#pragma unroll
        for (int j = 0; j < 4; j++) acc[j] = h2f(a0[j]) + h2f(a1[j]);
        l = Lp[(size_t)row * NH + hh] + Lp[(size_t)(1024 + row) * NH + hh];
    } else {
        const size_t j4 = (size_t)(row - 1024) * DOUT + (i4 & 2047);
        ushort4v b0 = *(const ushort4v*)(OpW + (size_t)2 * 1024 * DOUT + j4);
        ushort4v b1 = *(const ushort4v*)(OpW + (size_t)3 * 1024 * DOUT + j4);
        ushort4v b2 = *(const ushort4v*)(OpW + (size_t)4 * 1024 * DOUT + j4);
        ushort4v b3 = *(const ushort4v*)(OpD + j4);
#pragma unroll
        for (int j = 0; j < 4; j++)
            acc[j] = (h2f(b0[j]) + h2f(b1[j])) + (h2f(b2[j]) + h2f(b3[j]));
        const size_t lr = (size_t)(row - 1024) * NH + hh;
        l = (Lp[(size_t)2 * 1024 * NH + lr] + Lp[(size_t)3 * 1024 * NH + lr]) +
            (Lp[(size_t)4 * 1024 * NH + lr] + Lp[(size_t)5 * 1024 * NH + lr]);
    }
    const float inv = 1.0f / l;
    ushort4v r;
#pragma unroll
    for (int j = 0; j < 4; j++) r[j] = f2bf(acc[j] * inv);
    *(ushort4v*)(CTX + i4) = r;
}

// ---------------------------------------------------------------------------
extern "C" void kernel_launch(void* const* d_in, const int* in_sizes, int n_in,
                              void* d_out, int out_size, void* d_ws, size_t ws_size,
                              hipStream_t stream) {
    const float* x    = (const float*)d_in[0];
    const float* cosb = (const float*)d_in[2];
    const float* sinb = (const float*)d_in[3];
    const float* Wq   = (const float*)d_in[4];
    const float* Wk   = (const float*)d_in[5];
    const float* Wv   = (const float*)d_in[6];
    const float* Wo   = (const float*)d_in[7];
    const float* qw   = (const float*)d_in[8];
    const float* kw   = (const float*)d_in[9];
    float* out = (float*)d_out;

    // ws layout (41.9 MB):
    //   W1  [0, 12.58M)      qkv weights^T bf16   -- dead after gemm_qkv
    //   XB  [12.58, 20.97M)  x bf16               -- dead after gemm_qkv
    //   WoT [20.97, 29.36M)  Wo^T bf16            -- live until out-proj
    //   QKV [29.36, 41.94M)  q|k|v bf16           -- dead after flash
    // flash partials: A0,A1,B0,B1,B2 OVERLAY W1+XB (exactly 5 x 4.19M fp16);
    // B3 (4.19M fp16) + 6 L slots (786K fp32) live at the START of d_out
    // (d_out is dead until out-proj; combine runs before it).
    // combine writes ctx bf16 into the dead QKV region; out-proj reads it.
    unsigned short* W1  = (unsigned short*)d_ws;
    unsigned short* XB  = W1 + (size_t)QKVN * DIN;
    unsigned short* WoT = XB + (size_t)S_LEN * DIN;
    unsigned short* QKV = WoT + (size_t)DIN * DOUT;
    unsigned short* OpW = (unsigned short*)d_ws;
    unsigned short* OpD = (unsigned short*)d_out;
    float*          Lp  = (float*)(OpD + (size_t)1024 * DOUT);
    unsigned short* CTX = QKV;

    dim3 blk256(256);

    prep<<<dim3(14336), blk256, 0, stream>>>(Wq, Wk, Wv, Wo, x, W1, WoT, XB);

    gemm64<1><<<dim3(QKVN / 64, S_LEN / 128), blk256, 0, stream>>>(
        XB, W1, QKV, S_LEN, QKVN, DIN, qw, kw, cosb, sinb);

    // 1024 uniform blocks: 8 kv-heads x 32 qtile-pairs x 4 chunks {9,8,8,8}
    flash_part<<<dim3(NKV * 32 * 4), blk256, 0, stream>>>(
        QKV, QKV + KOFF, QKV + VOFF, OpW, OpD, Lp);

    combine<<<dim3(S_LEN * DOUT / 1024), blk256, 0, stream>>>(OpW, OpD, Lp, CTX);

    gemm64<0><<<dim3(DIN / 64, S_LEN / 128), blk256, 0, stream>>>(
        CTX, WoT, out, S_LEN, DIN, DOUT, nullptr, nullptr, nullptr, nullptr);
}

// Round 6
// 243.176 us; speedup vs baseline: 1.0341x; 1.0341x over previous
//
#include <hip/hip_runtime.h>
#include <hip/hip_bf16.h>
#include <math.h>

#define S_LEN 2048
#define DIN   2048
#define NH    32
#define NKV   8
#define HD    64
#define DOUT  2048        // NH*HD
#define QKVN  3072        // DOUT + 2*KVD
#define KOFF  2048        // k col offset in qkv
#define VOFF  2560        // v col offset in qkv

typedef __attribute__((ext_vector_type(8))) short short8v;    // 8 bf16 (4 VGPRs)
typedef __attribute__((ext_vector_type(8))) unsigned short ushort8v;
typedef __attribute__((ext_vector_type(4))) unsigned short ushort4v;
typedef __attribute__((ext_vector_type(4))) float float4v;
typedef __attribute__((ext_vector_type(16))) float float16v;

__device__ __forceinline__ float bf2f(unsigned short u) {
    union { float f; unsigned u; } c; c.u = ((unsigned)u) << 16; return c.f;
}
__device__ __forceinline__ unsigned short f2bf(float f) {
    union { float f; unsigned u; } c; c.f = f;
    unsigned r = c.u + 0x7fffu + ((c.u >> 16) & 1u);   // RNE
    return (unsigned short)(r >> 16);
}
__device__ __forceinline__ unsigned short f2h(float f) {
    union { _Float16 h; unsigned short u; } c; c.h = (_Float16)f; return c.u;
}
__device__ __forceinline__ float h2f(unsigned short u) {
    union { _Float16 h; unsigned short u; } c; c.u = u; return (float)c.h;
}
__device__ __forceinline__ unsigned cvtpk(float lo, float hi) {
    unsigned r;
    asm("v_cvt_pk_bf16_f32 %0, %1, %2" : "=v"(r) : "v"(lo), "v"(hi));
    return r;
}
__device__ __forceinline__ float fexp2(float x) {           // guaranteed 1 trans op
    float r;
    asm("v_exp_f32 %0, %1" : "=v"(r) : "v"(x));
    return r;
}

// ---------------------------------------------------------------------------
// Fused preprocessing, ONE launch, grid sections:
//   [0, 6144)        : Wq|Wk|Wv fp32 [K][N] -> bf16 [N][K] into W1 (32x32 tiles)
//   [6144, 10240)    : Wo transpose into WoT
//   [10240, 14336)   : x fp32 -> bf16 cast into XB
// ---------------------------------------------------------------------------
__global__ __launch_bounds__(256) void prep(const float* __restrict__ Wq,
                                            const float* __restrict__ Wk,
                                            const float* __restrict__ Wv,
                                            const float* __restrict__ Wo,
                                            const float* __restrict__ x,
                                            unsigned short* __restrict__ W1,
                                            unsigned short* __restrict__ WoT,
                                            unsigned short* __restrict__ XB) {
    __shared__ float t[32][33];
    const int a = blockIdx.x;
    const int tx = threadIdx.x & 31, ty = threadIdx.x >> 5;
    if (a < 6144) {                       // qkv weights: grid (96, 64)
        const int n0 = (a % 96) * 32, k0 = (a / 96) * 32;
        const float* src; int nn0, Nsrc;
        if (n0 < KOFF)      { src = Wq; nn0 = n0;        Nsrc = DOUT; }
        else if (n0 < VOFF) { src = Wk; nn0 = n0 - KOFF; Nsrc = 512; }
        else                { src = Wv; nn0 = n0 - VOFF; Nsrc = 512; }
#pragma unroll
        for (int j = ty; j < 32; j += 8)
            t[j][tx] = src[(size_t)(k0 + j) * Nsrc + nn0 + tx];
        __syncthreads();
#pragma unroll
        for (int j = ty; j < 32; j += 8)
            W1[(size_t)(n0 + j) * DIN + k0 + tx] = f2bf(t[tx][j]);
    } else if (a < 10240) {               // Wo: grid (64, 64), K=DOUT rows, N=DIN
        const int b = a - 6144;
        const int n0 = (b % 64) * 32, k0 = (b / 64) * 32;
#pragma unroll
        for (int j = ty; j < 32; j += 8)
            t[j][tx] = Wo[(size_t)(k0 + j) * DIN + n0 + tx];
        __syncthreads();
#pragma unroll
        for (int j = ty; j < 32; j += 8)
            WoT[(size_t)(n0 + j) * DOUT + k0 + tx] = f2bf(t[tx][j]);
    } else {                              // x cast: 4096 blocks x 1024 elems
        const int i = (a - 10240) * 1024 + threadIdx.x * 4;
        float4 v = *(const float4*)(x + i);
        XB[i + 0] = f2bf(v.x); XB[i + 1] = f2bf(v.y);
        XB[i + 2] = f2bf(v.z); XB[i + 3] = f2bf(v.w);
    }
}

// ---------------------------------------------------------------------------
// bf16 MFMA GEMM v2: 128x64 tile, BK=64, 4 waves stacked in M (wave = 32x64).
//   * Double-buffered LDS + counted vmcnt (T3/T4): prefetch in flight across
//     the barrier. T2 XOR swizzle via pre-swizzled global source. setprio(1)
//     around MFMA cluster.
// FUSE=1: bf16 out + per-head RMSNorm+RoPE epilogue (block col = one head).
// FUSE=0: fp32 out, plain.
// ---------------------------------------------------------------------------
template <int FUSE>
__global__ __launch_bounds__(256) void gemm64(const unsigned short* __restrict__ A,
                                              const unsigned short* __restrict__ Bt,
                                              void* __restrict__ Cv, int M, int N, int K,
                                              const float* __restrict__ qnw,
                                              const float* __restrict__ knw,
                                              const float* __restrict__ cosb,
                                              const float* __restrict__ sinb) {
    __shared__ __attribute__((aligned(16))) unsigned short As[2 * 128 * 64];
    __shared__ __attribute__((aligned(16))) unsigned short Bs[2 * 64 * 64];
    const int tid = threadIdx.x, lane = tid & 63, w = tid >> 6;
    const int bm = blockIdx.y * 128, bn = blockIdx.x * 64;
    const int wm = w * 32;

    float4v acc[2][4];
#pragma unroll
    for (int i = 0; i < 2; i++)
#pragma unroll
        for (int j = 0; j < 4; j++) acc[i][j] = (float4v){0.f, 0.f, 0.f, 0.f};

    const int srow = lane >> 3;
    const int schk = (lane & 7) ^ srow;
    const unsigned short* Ag[4];
    const unsigned short* Bg[2];
#pragma unroll
    for (int g = 0; g < 4; g++)
        Ag[g] = A + (size_t)(bm + w * 32 + g * 8 + srow) * K + schk * 8;
#pragma unroll
    for (int g = 0; g < 2; g++)
        Bg[g] = Bt + (size_t)(bn + w * 16 + g * 8 + srow) * K + schk * 8;

    auto STAGE = [&](int t, int b) {
        const size_t ko = (size_t)t * 64;
        unsigned short* Ad = As + b * (128 * 64) + (w * 32) * 64;
        unsigned short* Bd = Bs + b * (64 * 64) + (w * 16) * 64;
#pragma unroll
        for (int g = 0; g < 4; g++)
            __builtin_amdgcn_global_load_lds(
                (const __attribute__((address_space(1))) void*)(Ag[g] + ko),
                (__attribute__((address_space(3))) void*)(Ad + g * 8 * 64), 16, 0, 0);
#pragma unroll
        for (int g = 0; g < 2; g++)
            __builtin_amdgcn_global_load_lds(
                (const __attribute__((address_space(1))) void*)(Bg[g] + ko),
                (__attribute__((address_space(3))) void*)(Bd + g * 8 * 64), 16, 0, 0);
    };

    const int frow = lane & 15, quad = lane >> 4, sw = frow & 7;
    const int NT = K >> 6;

    STAGE(0, 0);                                   // prologue: tile 0 -> buf 0

    for (int t = 0; t < NT; t++) {
        const int c = t & 1;
        if (t + 1 < NT) {
            STAGE(t + 1, c ^ 1);
            asm volatile("s_waitcnt vmcnt(6)" ::: "memory");   // tile t done
        } else {
            asm volatile("s_waitcnt vmcnt(0)" ::: "memory");
        }
        __builtin_amdgcn_s_barrier();
        __builtin_amdgcn_sched_barrier(0);

        const unsigned short* Ab = As + c * (128 * 64);
        const unsigned short* Bb = Bs + c * (64 * 64);
        short8v af[2][2], bf[4][2];
#pragma unroll
        for (int fm = 0; fm < 2; fm++)
#pragma unroll
            for (int ks = 0; ks < 2; ks++)
                af[fm][ks] = *(const short8v*)(Ab + (wm + fm * 16 + frow) * 64 +
                                               (((ks * 4 + quad) ^ sw) * 8));
#pragma unroll
        for (int fn = 0; fn < 4; fn++)
#pragma unroll
            for (int ks = 0; ks < 2; ks++)
                bf[fn][ks] = *(const short8v*)(Bb + (fn * 16 + frow) * 64 +
                                               (((ks * 4 + quad) ^ sw) * 8));
        __builtin_amdgcn_s_setprio(1);
#pragma unroll
        for (int ks = 0; ks < 2; ks++)
#pragma unroll
            for (int fm = 0; fm < 2; fm++)
#pragma unroll
                for (int fn = 0; fn < 4; fn++)
                    acc[fm][fn] = __builtin_amdgcn_mfma_f32_16x16x32_bf16(
                        af[fm][ks], bf[fn][ks], acc[fm][fn], 0, 0, 0);
        __builtin_amdgcn_s_setprio(0);

        if (t + 1 < NT) {
            asm volatile("s_waitcnt lgkmcnt(0)" ::: "memory");  // reads pulled
            __builtin_amdgcn_sched_barrier(0);
            __builtin_amdgcn_s_barrier();          // buf c free to overwrite
        }
    }

    const int quad4 = lane >> 4, col16 = lane & 15;
    if constexpr (FUSE == 1) {
        unsigned short* C = (unsigned short*)Cv;
        const int head = bn >> 6;                 // one head per block col
        if (head < 40) {
            const float* nw = (head < 32) ? qnw : knw;
            float wv[4];
#pragma unroll
            for (int fn = 0; fn < 4; fn++) wv[fn] = nw[fn * 16 + col16];
#pragma unroll
            for (int fm = 0; fm < 2; fm++)
#pragma unroll
                for (int r = 0; r < 4; r++) {
                    float x0 = acc[fm][0][r], x1 = acc[fm][1][r];
                    float x2 = acc[fm][2][r], x3 = acc[fm][3][r];
                    float ss = x0 * x0 + x1 * x1 + x2 * x2 + x3 * x3;
                    ss += __shfl_xor(ss, 1); ss += __shfl_xor(ss, 2);
                    ss += __shfl_xor(ss, 4); ss += __shfl_xor(ss, 8);
                    const float inv = rsqrtf(ss * (1.0f / 64.0f) + 1e-6f);
                    float xn[4] = {x0 * inv * wv[0], x1 * inv * wv[1],
                                   x2 * inv * wv[2], x3 * inv * wv[3]};
                    const int row = bm + wm + fm * 16 + quad4 * 4 + r;
                    const float* cr = cosb + (size_t)row * HD;
                    const float* sr = sinb + (size_t)row * HD;
#pragma unroll
                    for (int fn = 0; fn < 4; fn++) {
                        const float rot = (fn < 2) ? -xn[fn + 2] : xn[fn - 2];
                        const float res = xn[fn] * cr[fn * 16 + col16] +
                                          rot * sr[fn * 16 + col16];
                        C[(size_t)row * N + bn + fn * 16 + col16] = f2bf(res);
                    }
                }
        } else {
#pragma unroll
            for (int fm = 0; fm < 2; fm++)
#pragma unroll
                for (int fn = 0; fn < 4; fn++)
#pragma unroll
                    for (int r = 0; r < 4; r++)
                        C[(size_t)(bm + wm + fm * 16 + quad4 * 4 + r) * N +
                          bn + fn * 16 + col16] = f2bf(acc[fm][fn][r]);
        }
    } else {
        float* C = (float*)Cv;
#pragma unroll
        for (int fm = 0; fm < 2; fm++)
#pragma unroll
            for (int fn = 0; fn < 4; fn++)
#pragma unroll
                for (int r = 0; r < 4; r++)
                    C[(size_t)(bm + wm + fm * 16 + quad4 * 4 + r) * N +
                      bn + fn * 16 + col16] = acc[fm][fn][r];
    }
}

// ---------------------------------------------------------------------------
// MFMA flash attention v9 (causal, GQA), fixed-max softmax.
//   * v8 structure (4 chunks {9,8,8,8} per qtile-pair, 1024 blocks, KSTR=72,
//     LDS 36864 B -> 4 blocks/CU by LDS) but WITHOUT the VGPR-64 cap:
//     launch_bounds(256,3) (the v7 regime, VGPR ~84-96 <= 128) so the HW
//     still schedules 4 blocks/CU (16 waves/CU = 4 waves/SIMD) and the
//     2-deep prefetch keeps its registers (v8's (256,4) forced VGPR 64 ->
//     spills: FETCH 14->30MB, WRITE 45->106MB, dur 45->57us).
//   * Zero-partial skip: chunk1 writes no A1 when it has no qa tiles
//     (nta<=9 <=> p<=17); chunk0 writes no B0 when all-qa (nta>=9 <=> p>=16).
//     Combine: A1 valid <=> row>=576; B0 valid <=> row>=1536 (wave-uniform).
//   * Everything else proven: swapped QK^T, permlane32_swap, Lacc on MFMA,
//     dbuf K/V + 2-deep reg prefetch, one barrier/tile.
// ---------------------------------------------------------------------------
#define KSTR 72    // K/V LDS row stride (shorts); 2*2*64*72*2B = 36864 B

__global__ __launch_bounds__(256, 3) void flash_part(const unsigned short* __restrict__ qb,
                                                     const unsigned short* __restrict__ kb,
                                                     const unsigned short* __restrict__ vb,
                                                     unsigned short* __restrict__ OpW,
                                                     unsigned short* __restrict__ OpD,
                                                     float* __restrict__ Lp) {
    __shared__ __attribute__((aligned(16))) unsigned short Ks[2][64 * KSTR];
    __shared__ __attribute__((aligned(16))) unsigned short Vt[2][64 * KSTR];

    const int tid = threadIdx.x, lane = tid & 63, w = tid >> 6;
    const int sl = lane & 31, hi = lane >> 5, hi8 = hi * 8;
    const int bid = blockIdx.x;
    const int g = bid & 7;                    // kv head
    const int p = (bid >> 3) & 31;            // pair index: qtiles p and 63-p
    const int c = bid >> 8;                   // chunk 0..3
    const int h = g * 4 + w;

    const int co   = c ? (9 + (c - 1) * 8) : 0;   // chunk offsets {0,9,17,25}
    const int clen = c ? 8 : 9;                   // chunk lengths {9,8,8,8}

    const int s0a = p * 32, s0b = (63 - p) * 32;
    const int nta = (s0a + 95) >> 6;          // 1..16 (qa tiles; qb = 33-nta)
    int nA = nta - co;                        // qa tiles in this window
    nA = nA < 0 ? 0 : (nA > clen ? clen : nA);

    const float C1 = 0.18033688011112042f;    // 0.125 * log2(e)
    const float C2 = 12.262908856239697f;     // 8.5  * log2(e)

    // partial slots: A_c (c<2) rows [0,1024); B_c rows [1024,2048)
    unsigned short* OhA = OpW + (size_t)c * 1024 * DOUT;
    float*          LhA = Lp + (size_t)c * 1024 * NH;
    unsigned short* OhB = (c < 3) ? (OpW + (size_t)(2 + c) * 1024 * DOUT) : OpD;
    float*          LhB = Lp + (size_t)(2 + c) * 1024 * NH;

    int seg = (c < 2) ? 0 : 1;                // chunks 2,3 are all-qb
    int s0 = seg == 0 ? s0a : s0b;

    // Q fragments (B-operand layout): lane holds Q[s0+sl][16*ksq + 8*hi + j]
    short8v qf[4];
#pragma unroll
    for (int ksq = 0; ksq < 4; ksq++)
        qf[ksq] = *(const short8v*)(qb + (size_t)(s0 + sl) * QKVN + h * HD +
                                    ksq * 16 + hi8);

    float16v O[2], Lacc;
#pragma unroll
    for (int df = 0; df < 2; df++)
#pragma unroll
        for (int r = 0; r < 16; r++) O[df][r] = 0.f;
#pragma unroll
    for (int r = 0; r < 16; r++) Lacc[r] = 0.f;

    short8v ones;
#pragma unroll
    for (int i = 0; i < 8; i++) ones[i] = (short)0x3F80;   // bf16 1.0

    // staging addresses
    const int kkey = tid >> 2, kch = tid & 3;     // K: 4 threads/key, 16 shorts
    const unsigned short* kg = kb + (size_t)kkey * QKVN + g * HD + kch * 16;
    const int kp = tid & 31, vdbb = tid >> 5;     // V: keys 2kp,2kp+1; dims vdbb*8..+8
    const unsigned short* vg0 = vb + (size_t)(2 * kp) * QKVN + g * HD + vdbb * 8;
    const unsigned short* vg1 = vg0 + QKVN;

    auto epi = [&](int sbase, unsigned short* Os, float* Ls, int roff) {
#pragma unroll
        for (int df = 0; df < 2; df++)
#pragma unroll
            for (int r = 0; r < 16; r++) {
                const int row = sbase + (r & 3) + 8 * (r >> 2) + 4 * hi - roff;
                Os[(size_t)row * DOUT + h * HD + df * 32 + sl] = f2h(O[df][r]);
            }
        if (sl == 0) {
#pragma unroll
            for (int r = 0; r < 16; r++) {
                const int row = sbase + (r & 3) + 8 * (r >> 2) + 4 * hi - roff;
                Ls[(size_t)row * NH + h] = Lacc[r];
            }
        }
    };
    auto zacc = [&]() {
#pragma unroll
        for (int df = 0; df < 2; df++)
#pragma unroll
            for (int r = 0; r < 16; r++) O[df][r] = 0.f;
#pragma unroll
        for (int r = 0; r < 16; r++) Lacc[r] = 0.f;
    };

    auto kt = [&](int jj) {                   // key-tile index for stream pos jj
        const int sj = co + jj;
        return (sj < nta) ? sj : (sj - nta);
    };

    ushort8v ka0, ka1, va0, va1;
    auto LOADREGS = [&](int it) {
        const size_t off = (size_t)it * 64 * QKVN;
        ka0 = *(const ushort8v*)(kg + off);
        ka1 = *(const ushort8v*)(kg + off + 8);
        va0 = *(const ushort8v*)(vg0 + off);
        va1 = *(const ushort8v*)(vg1 + off);
    };
    auto COMMIT = [&](int b) {
        unsigned short* kd = Ks[b] + kkey * KSTR + kch * 16;
        *(ushort8v*)kd = ka0;
        *(ushort8v*)(kd + 8) = ka1;
        union { ushort8v v; unsigned d[4]; } ua, ub;
        ua.v = va0; ub.v = va1;
        unsigned short* vd = Vt[b] + (size_t)(vdbb * 8) * KSTR + 2 * kp;
#pragma unroll
        for (int i = 0; i < 8; i++) {
            const unsigned sel = (i & 1) ? 0x07060302u : 0x05040100u;
            const unsigned word = __builtin_amdgcn_perm(ub.d[i >> 1], ua.d[i >> 1], sel);
            *(unsigned*)(vd + (size_t)i * KSTR) = word;
        }
    };

    // prologue: tile0 -> regs -> buf0; tile1 -> regs
    LOADREGS(kt(0));
    COMMIT(0);
    LOADREGS(kt(1));

#pragma unroll 1
    for (int jj = 0; jj < clen; jj++) {
        const int cur = jj & 1;
        __syncthreads();                    // buf[cur] committed; prev reads done
        if (jj + 1 < clen) COMMIT(cur ^ 1); // regs hold tile jj+1
        if (jj + 2 < clen) LOADREGS(kt(jj + 2));
        if (seg == 0 && jj == nA) {         // qa -> qb boundary
            if (nA) {                       // flush A partial only if non-zero
                epi(s0a, OhA, LhA, 0);
                zacc();
            }
            s0 = s0b; seg = 1;
#pragma unroll
            for (int ksq = 0; ksq < 4; ksq++)
                qf[ksq] = *(const short8v*)(qb + (size_t)(s0b + sl) * QKVN +
                                            h * HD + ksq * 16 + hi8);
        }

        const int t0 = kt(jj) * 64;
        const bool edge = (t0 + 63 > s0);

#pragma unroll
        for (int b = 0; b < 2; b++) {
            short8v kf[4];
#pragma unroll
            for (int ksq = 0; ksq < 4; ksq++)
                kf[ksq] = *(const short8v*)(Ks[cur] + (32 * b + sl) * KSTR +
                                            ksq * 16 + hi8);
            float16v sct;
#pragma unroll
            for (int r = 0; r < 16; r++) sct[r] = 0.f;
            __builtin_amdgcn_s_setprio(1);
#pragma unroll
            for (int ksq = 0; ksq < 4; ksq++)
                sct = __builtin_amdgcn_mfma_f32_32x32x16_bf16(kf[ksq], qf[ksq],
                                                              sct, 0, 0, 0);
            __builtin_amdgcn_s_setprio(0);
#pragma unroll
            for (int r = 0; r < 16; r++) {
                float arg = sct[r] * C1 - C2;
                if (edge) {
                    const int kglob = t0 + 32 * b + (r & 3) + 8 * (r >> 2) + 4 * hi;
                    arg = (kglob <= s0 + sl) ? arg : -100.f;
                }
                sct[r] = fexp2(arg);
            }
            unsigned pk[8];
#pragma unroll
            for (int i = 0; i < 8; i++) pk[i] = cvtpk(sct[2 * i], sct[2 * i + 1]);
#pragma unroll
            for (int kk = 0; kk < 2; kk++) {
                unsigned x0 = pk[4 * kk + 0], x1 = pk[4 * kk + 1];
                unsigned y0 = pk[4 * kk + 2], y1 = pk[4 * kk + 3];
                // halves swap: x' = {x_lo, y_lo}, y' = {x_hi, y_hi}
                asm("v_permlane32_swap_b32 %0, %1" : "+v"(x0), "+v"(y0));
                asm("v_permlane32_swap_b32 %0, %1" : "+v"(x1), "+v"(y1));
                union { unsigned u[4]; short8v v; } pa;
                pa.u[0] = x0; pa.u[1] = x1; pa.u[2] = y0; pa.u[3] = y1;
                const int ks = 2 * b + kk;
                __builtin_amdgcn_s_setprio(1);
#pragma unroll
                for (int df = 0; df < 2; df++) {
                    const short8v vf = *(const short8v*)(Vt[cur] +
                                                         (size_t)(df * 32 + sl) * KSTR +
                                                         ks * 16 + hi8);
                    O[df] = __builtin_amdgcn_mfma_f32_32x32x16_bf16(pa.v, vf,
                                                                    O[df], 0, 0, 0);
                }
                Lacc = __builtin_amdgcn_mfma_f32_32x32x16_bf16(pa.v, ones,
                                                               Lacc, 0, 0, 0);
                __builtin_amdgcn_s_setprio(0);
            }
        }
    }

    if (seg == 0) {            // chunk0 all-qa: flush A, B partial SKIPPED
        epi(s0a, OhA, LhA, 0); // (combine knows B0 invalid for rows < 1536)
    } else {
        epi(s0b, OhB, LhB, 1024);
    }
}

// ---------------------------------------------------------------------------
// Combine with validity masks (wave-uniform per block):
//   rows [0,576):      A0               rows [576,1024):  A0+A1
//   rows [1024,1536):  B1+B2+B3         rows [1536,2048): B0+B1+B2+B3
// ctx (bf16) written to CTX (the dead QKV region).
// ---------------------------------------------------------------------------
__global__ __launch_bounds__(256) void combine(const unsigned short* __restrict__ OpW,
                                               const unsigned short* __restrict__ OpD,
                                               const float* __restrict__ Lp,
                                               unsigned short* __restrict__ CTX) {
    const int i4 = (blockIdx.x * 256 + threadIdx.x) * 4;
    const int row = i4 >> 11, hh = (i4 & 2047) >> 6;
    float acc[4];
    float l;
    if (row < 1024) {
        ushort4v a0 = *(const ushort4v*)(OpW + i4);
#pragma unroll
        for (int j = 0; j < 4; j++) acc[j] = h2f(a0[j]);
        l = Lp[(size_t)row * NH + hh];
        if (row >= 576) {                 // A1 valid (chunk1 had qa tiles)
            ushort4v a1 = *(const ushort4v*)(OpW + (size_t)1024 * DOUT + i4);
#pragma unroll
            for (int j = 0; j < 4; j++) acc[j] += h2f(a1[j]);
            l += Lp[(size_t)(1024 + row) * NH + hh];
        }
    } else {
        const size_t j4 = (size_t)(row - 1024) * DOUT + (i4 & 2047);
        ushort4v b1 = *(const ushort4v*)(OpW + (size_t)3 * 1024 * DOUT + j4);
        ushort4v b2 = *(const ushort4v*)(OpW + (size_t)4 * 1024 * DOUT + j4);
        ushort4v b3 = *(const ushort4v*)(OpD + j4);
#pragma unroll
        for (int j = 0; j < 4; j++)
            acc[j] = h2f(b1[j]) + h2f(b2[j]) + h2f(b3[j]);
        const size_t lr = (size_t)(row - 1024) * NH + hh;
        l = Lp[(size_t)3 * 1024 * NH + lr] + Lp[(size_t)4 * 1024 * NH + lr] +
            Lp[(size_t)5 * 1024 * NH + lr];
        if (row >= 1536) {                // B0 valid (chunk0 reached qb)
            ushort4v b0 = *(const ushort4v*)(OpW + (size_t)2 * 1024 * DOUT + j4);
#pragma unroll
            for (int j = 0; j < 4; j++) acc[j] += h2f(b0[j]);
            l += Lp[(size_t)2 * 1024 * NH + lr];
        }
    }
    const float inv = 1.0f / l;
    ushort4v r;
#pragma unroll
    for (int j = 0; j < 4; j++) r[j] = f2bf(acc[j] * inv);
    *(ushort4v*)(CTX + i4) = r;
}

// ---------------------------------------------------------------------------
extern "C" void kernel_launch(void* const* d_in, const int* in_sizes, int n_in,
                              void* d_out, int out_size, void* d_ws, size_t ws_size,
                              hipStream_t stream) {
    const float* x    = (const float*)d_in[0];
    const float* cosb = (const float*)d_in[2];
    const float* sinb = (const float*)d_in[3];
    const float* Wq   = (const float*)d_in[4];
    const float* Wk   = (const float*)d_in[5];
    const float* Wv   = (const float*)d_in[6];
    const float* Wo   = (const float*)d_in[7];
    const float* qw   = (const float*)d_in[8];
    const float* kw   = (const float*)d_in[9];
    float* out = (float*)d_out;

    // ws layout (41.9 MB):
    //   W1  [0, 12.58M)      qkv weights^T bf16   -- dead after gemm_qkv
    //   XB  [12.58, 20.97M)  x bf16               -- dead after gemm_qkv
    //   WoT [20.97, 29.36M)  Wo^T bf16            -- live until out-proj
    //   QKV [29.36, 41.94M)  q|k|v bf16           -- dead after flash
    // flash partials: A0,A1,B0,B1,B2 OVERLAY W1+XB (exactly 5 x 4.19M fp16);
    // B3 (4.19M fp16) + 6 L slots (786K fp32) live at the START of d_out
    // (d_out is dead until out-proj; combine runs before it).
    // combine writes ctx bf16 into the dead QKV region; out-proj reads it.
    unsigned short* W1  = (unsigned short*)d_ws;
    unsigned short* XB  = W1 + (size_t)QKVN * DIN;
    unsigned short* WoT = XB + (size_t)S_LEN * DIN;
    unsigned short* QKV = WoT + (size_t)DIN * DOUT;
    unsigned short* OpW = (unsigned short*)d_ws;
    unsigned short* OpD = (unsigned short*)d_out;
    float*          Lp  = (float*)(OpD + (size_t)1024 * DOUT);
    unsigned short* CTX = QKV;

    dim3 blk256(256);

    prep<<<dim3(14336), blk256, 0, stream>>>(Wq, Wk, Wv, Wo, x, W1, WoT, XB);

    gemm64<1><<<dim3(QKVN / 64, S_LEN / 128), blk256, 0, stream>>>(
        XB, W1, QKV, S_LEN, QKVN, DIN, qw, kw, cosb, sinb);

    // 1024 uniform blocks: 8 kv-heads x 32 qtile-pairs x 4 chunks {9,8,8,8}
    flash_part<<<dim3(NKV * 32 * 4), blk256, 0, stream>>>(
        QKV, QKV + KOFF, QKV + VOFF, OpW, OpD, Lp);

    combine<<<dim3(S_LEN * DOUT / 1024), blk256, 0, stream>>>(OpW, OpD, Lp, CTX);

    gemm64<0><<<dim3(DIN / 64, S_LEN / 128), blk256, 0, stream>>>(
        CTX, WoT, out, S_LEN, DIN, DOUT, nullptr, nullptr, nullptr, nullptr);
}

// Round 7
// 234.004 us; speedup vs baseline: 1.0747x; 1.0392x over previous
//
#include <hip/hip_runtime.h>
#include <hip/hip_bf16.h>
#include <math.h>

#define S_LEN 2048
#define DIN   2048
#define NH    32
#define NKV   8
#define HD    64
#define DOUT  2048        // NH*HD
#define QKVN  3072        // DOUT + 2*KVD
#define KOFF  2048        // k col offset in qkv
#define VOFF  2560        // v col offset in qkv

typedef __attribute__((ext_vector_type(8))) short short8v;    // 8 bf16 (4 VGPRs)
typedef __attribute__((ext_vector_type(8))) unsigned short ushort8v;
typedef __attribute__((ext_vector_type(4))) unsigned short ushort4v;
typedef __attribute__((ext_vector_type(4))) float float4v;
typedef __attribute__((ext_vector_type(16))) float float16v;

__device__ __forceinline__ float bf2f(unsigned short u) {
    union { float f; unsigned u; } c; c.u = ((unsigned)u) << 16; return c.f;
}
__device__ __forceinline__ unsigned short f2bf(float f) {
    union { float f; unsigned u; } c; c.f = f;
    unsigned r = c.u + 0x7fffu + ((c.u >> 16) & 1u);   // RNE
    return (unsigned short)(r >> 16);
}
__device__ __forceinline__ unsigned short f2h(float f) {
    union { _Float16 h; unsigned short u; } c; c.h = (_Float16)f; return c.u;
}
__device__ __forceinline__ float h2f(unsigned short u) {
    union { _Float16 h; unsigned short u; } c; c.u = u; return (float)c.h;
}
__device__ __forceinline__ unsigned cvtpk(float lo, float hi) {
    unsigned r;
    asm("v_cvt_pk_bf16_f32 %0, %1, %2" : "=v"(r) : "v"(lo), "v"(hi));
    return r;
}
__device__ __forceinline__ float fexp2(float x) {           // guaranteed 1 trans op
    float r;
    asm("v_exp_f32 %0, %1" : "=v"(r) : "v"(x));
    return r;
}

// ---------------------------------------------------------------------------
// Fused preprocessing, ONE launch, grid sections:
//   [0, 6144)        : Wq|Wk|Wv fp32 [K][N] -> bf16 [N][K] into W1 (32x32 tiles)
//   [6144, 10240)    : Wo transpose into WoT
//   [10240, 14336)   : x fp32 -> bf16 cast into XB
// ---------------------------------------------------------------------------
__global__ __launch_bounds__(256) void prep(const float* __restrict__ Wq,
                                            const float* __restrict__ Wk,
                                            const float* __restrict__ Wv,
                                            const float* __restrict__ Wo,
                                            const float* __restrict__ x,
                                            unsigned short* __restrict__ W1,
                                            unsigned short* __restrict__ WoT,
                                            unsigned short* __restrict__ XB) {
    __shared__ float t[32][33];
    const int a = blockIdx.x;
    const int tx = threadIdx.x & 31, ty = threadIdx.x >> 5;
    if (a < 6144) {                       // qkv weights: grid (96, 64)
        const int n0 = (a % 96) * 32, k0 = (a / 96) * 32;
        const float* src; int nn0, Nsrc;
        if (n0 < KOFF)      { src = Wq; nn0 = n0;        Nsrc = DOUT; }
        else if (n0 < VOFF) { src = Wk; nn0 = n0 - KOFF; Nsrc = 512; }
        else                { src = Wv; nn0 = n0 - VOFF; Nsrc = 512; }
#pragma unroll
        for (int j = ty; j < 32; j += 8)
            t[j][tx] = src[(size_t)(k0 + j) * Nsrc + nn0 + tx];
        __syncthreads();
#pragma unroll
        for (int j = ty; j < 32; j += 8)
            W1[(size_t)(n0 + j) * DIN + k0 + tx] = f2bf(t[tx][j]);
    } else if (a < 10240) {               // Wo: grid (64, 64), K=DOUT rows, N=DIN
        const int b = a - 6144;
        const int n0 = (b % 64) * 32, k0 = (b / 64) * 32;
#pragma unroll
        for (int j = ty; j < 32; j += 8)
            t[j][tx] = Wo[(size_t)(k0 + j) * DIN + n0 + tx];
        __syncthreads();
#pragma unroll
        for (int j = ty; j < 32; j += 8)
            WoT[(size_t)(n0 + j) * DOUT + k0 + tx] = f2bf(t[tx][j]);
    } else {                              // x cast: 4096 blocks x 1024 elems
        const int i = (a - 10240) * 1024 + threadIdx.x * 4;
        float4 v = *(const float4*)(x + i);
        XB[i + 0] = f2bf(v.x); XB[i + 1] = f2bf(v.y);
        XB[i + 2] = f2bf(v.z); XB[i + 3] = f2bf(v.w);
    }
}

// ---------------------------------------------------------------------------
// bf16 MFMA GEMM v2: 128x64 tile, BK=64, 4 waves stacked in M (wave = 32x64).
//   * Double-buffered LDS + counted vmcnt (T3/T4): prefetch in flight across
//     the barrier. T2 XOR swizzle via pre-swizzled global source. setprio(1)
//     around MFMA cluster.
// FUSE=1: bf16 out + per-head RMSNorm+RoPE epilogue (block col = one head).
// FUSE=0: fp32 out, plain.
// ---------------------------------------------------------------------------
template <int FUSE>
__global__ __launch_bounds__(256) void gemm64(const unsigned short* __restrict__ A,
                                              const unsigned short* __restrict__ Bt,
                                              void* __restrict__ Cv, int M, int N, int K,
                                              const float* __restrict__ qnw,
                                              const float* __restrict__ knw,
                                              const float* __restrict__ cosb,
                                              const float* __restrict__ sinb) {
    __shared__ __attribute__((aligned(16))) unsigned short As[2 * 128 * 64];
    __shared__ __attribute__((aligned(16))) unsigned short Bs[2 * 64 * 64];
    const int tid = threadIdx.x, lane = tid & 63, w = tid >> 6;
    const int bm = blockIdx.y * 128, bn = blockIdx.x * 64;
    const int wm = w * 32;

    float4v acc[2][4];
#pragma unroll
    for (int i = 0; i < 2; i++)
#pragma unroll
        for (int j = 0; j < 4; j++) acc[i][j] = (float4v){0.f, 0.f, 0.f, 0.f};

    const int srow = lane >> 3;
    const int schk = (lane & 7) ^ srow;
    const unsigned short* Ag[4];
    const unsigned short* Bg[2];
#pragma unroll
    for (int g = 0; g < 4; g++)
        Ag[g] = A + (size_t)(bm + w * 32 + g * 8 + srow) * K + schk * 8;
#pragma unroll
    for (int g = 0; g < 2; g++)
        Bg[g] = Bt + (size_t)(bn + w * 16 + g * 8 + srow) * K + schk * 8;

    auto STAGE = [&](int t, int b) {
        const size_t ko = (size_t)t * 64;
        unsigned short* Ad = As + b * (128 * 64) + (w * 32) * 64;
        unsigned short* Bd = Bs + b * (64 * 64) + (w * 16) * 64;
#pragma unroll
        for (int g = 0; g < 4; g++)
            __builtin_amdgcn_global_load_lds(
                (const __attribute__((address_space(1))) void*)(Ag[g] + ko),
                (__attribute__((address_space(3))) void*)(Ad + g * 8 * 64), 16, 0, 0);
#pragma unroll
        for (int g = 0; g < 2; g++)
            __builtin_amdgcn_global_load_lds(
                (const __attribute__((address_space(1))) void*)(Bg[g] + ko),
                (__attribute__((address_space(3))) void*)(Bd + g * 8 * 64), 16, 0, 0);
    };

    const int frow = lane & 15, quad = lane >> 4, sw = frow & 7;
    const int NT = K >> 6;

    STAGE(0, 0);                                   // prologue: tile 0 -> buf 0

    for (int t = 0; t < NT; t++) {
        const int c = t & 1;
        if (t + 1 < NT) {
            STAGE(t + 1, c ^ 1);
            asm volatile("s_waitcnt vmcnt(6)" ::: "memory");   // tile t done
        } else {
            asm volatile("s_waitcnt vmcnt(0)" ::: "memory");
        }
        __builtin_amdgcn_s_barrier();
        __builtin_amdgcn_sched_barrier(0);

        const unsigned short* Ab = As + c * (128 * 64);
        const unsigned short* Bb = Bs + c * (64 * 64);
        short8v af[2][2], bf[4][2];
#pragma unroll
        for (int fm = 0; fm < 2; fm++)
#pragma unroll
            for (int ks = 0; ks < 2; ks++)
                af[fm][ks] = *(const short8v*)(Ab + (wm + fm * 16 + frow) * 64 +
                                               (((ks * 4 + quad) ^ sw) * 8));
#pragma unroll
        for (int fn = 0; fn < 4; fn++)
#pragma unroll
            for (int ks = 0; ks < 2; ks++)
                bf[fn][ks] = *(const short8v*)(Bb + (fn * 16 + frow) * 64 +
                                               (((ks * 4 + quad) ^ sw) * 8));
        __builtin_amdgcn_s_setprio(1);
#pragma unroll
        for (int ks = 0; ks < 2; ks++)
#pragma unroll
            for (int fm = 0; fm < 2; fm++)
#pragma unroll
                for (int fn = 0; fn < 4; fn++)
                    acc[fm][fn] = __builtin_amdgcn_mfma_f32_16x16x32_bf16(
                        af[fm][ks], bf[fn][ks], acc[fm][fn], 0, 0, 0);
        __builtin_amdgcn_s_setprio(0);

        if (t + 1 < NT) {
            asm volatile("s_waitcnt lgkmcnt(0)" ::: "memory");  // reads pulled
            __builtin_amdgcn_sched_barrier(0);
            __builtin_amdgcn_s_barrier();          // buf c free to overwrite
        }
    }

    const int quad4 = lane >> 4, col16 = lane & 15;
    if constexpr (FUSE == 1) {
        unsigned short* C = (unsigned short*)Cv;
        const int head = bn >> 6;                 // one head per block col
        if (head < 40) {
            const float* nw = (head < 32) ? qnw : knw;
            float wv[4];
#pragma unroll
            for (int fn = 0; fn < 4; fn++) wv[fn] = nw[fn * 16 + col16];
#pragma unroll
            for (int fm = 0; fm < 2; fm++)
#pragma unroll
                for (int r = 0; r < 4; r++) {
                    float x0 = acc[fm][0][r], x1 = acc[fm][1][r];
                    float x2 = acc[fm][2][r], x3 = acc[fm][3][r];
                    float ss = x0 * x0 + x1 * x1 + x2 * x2 + x3 * x3;
                    ss += __shfl_xor(ss, 1); ss += __shfl_xor(ss, 2);
                    ss += __shfl_xor(ss, 4); ss += __shfl_xor(ss, 8);
                    const float inv = rsqrtf(ss * (1.0f / 64.0f) + 1e-6f);
                    float xn[4] = {x0 * inv * wv[0], x1 * inv * wv[1],
                                   x2 * inv * wv[2], x3 * inv * wv[3]};
                    const int row = bm + wm + fm * 16 + quad4 * 4 + r;
                    const float* cr = cosb + (size_t)row * HD;
                    const float* sr = sinb + (size_t)row * HD;
#pragma unroll
                    for (int fn = 0; fn < 4; fn++) {
                        const float rot = (fn < 2) ? -xn[fn + 2] : xn[fn - 2];
                        const float res = xn[fn] * cr[fn * 16 + col16] +
                                          rot * sr[fn * 16 + col16];
                        C[(size_t)row * N + bn + fn * 16 + col16] = f2bf(res);
                    }
                }
        } else {
#pragma unroll
            for (int fm = 0; fm < 2; fm++)
#pragma unroll
                for (int fn = 0; fn < 4; fn++)
#pragma unroll
                    for (int r = 0; r < 4; r++)
                        C[(size_t)(bm + wm + fm * 16 + quad4 * 4 + r) * N +
                          bn + fn * 16 + col16] = f2bf(acc[fm][fn][r]);
        }
    } else {
        float* C = (float*)Cv;
#pragma unroll
        for (int fm = 0; fm < 2; fm++)
#pragma unroll
            for (int fn = 0; fn < 4; fn++)
#pragma unroll
                for (int r = 0; r < 4; r++)
                    C[(size_t)(bm + wm + fm * 16 + quad4 * 4 + r) * N +
                      bn + fn * 16 + col16] = acc[fm][fn][r];
    }
}

// ---------------------------------------------------------------------------
// MFMA flash attention v10 (causal, GQA), fixed-max softmax.
//   REVERT to the proven R4/v7 structure (45.1 us measured):
//   * 3 chunks of 11 tiles per qtile-pair (33 = 3*11): 768 blocks, KSTR=88,
//     LDS 45056 B, launch_bounds(256,3) -> 3 blocks/CU (reg-limited; v8/v9's
//     4-chunk split never got a 4th block resident: acc regs push the true
//     per-wave footprint past 128, so it only diluted per-block fixed costs).
//   * ALL O-partials in the d_ws overlay (v9's B3-in-d_out caused a 147 us
//     cold first dispatch: d_out is re-poisoned between iterations).
//   KEPT from v9 (strictly positive): zero-partial skip --
//     A1 written only when chunk1 has qa tiles (p>=22 <=> rows>=704);
//     B0 written only when chunk0 reaches qb (p<=19 <=> rows>=1408).
//   * Swapped QK^T, permlane32_swap P-redistribution, Lacc on matrix pipe,
//     dbuf K/V + 2-deep reg prefetch, one barrier/tile, setprio MFMA clusters.
// ---------------------------------------------------------------------------
#define KSTR 88    // K/V LDS row stride (shorts); 2*2*64*88*2B = 45056 B

__global__ __launch_bounds__(256, 3) void flash_part(const unsigned short* __restrict__ qb,
                                                     const unsigned short* __restrict__ kb,
                                                     const unsigned short* __restrict__ vb,
                                                     unsigned short* __restrict__ OpW,
                                                     float* __restrict__ Lp) {
    __shared__ __attribute__((aligned(16))) unsigned short Ks[2][64 * KSTR];
    __shared__ __attribute__((aligned(16))) unsigned short Vt[2][64 * KSTR];

    const int tid = threadIdx.x, lane = tid & 63, w = tid >> 6;
    const int sl = lane & 31, hi = lane >> 5, hi8 = hi * 8;
    const int bid = blockIdx.x;
    const int g = bid & 7;                    // kv head
    const int p = (bid >> 3) & 31;            // pair index: qtiles p and 63-p
    const int c = bid >> 8;                   // chunk 0..2
    const int h = g * 4 + w;

    const int co   = c * 11;                  // chunk offsets {0,11,22}
    const int clen = 11;

    const int s0a = p * 32, s0b = (63 - p) * 32;
    const int nta = (s0a + 95) >> 6;          // 1..16 (qa tiles; qb = 33-nta)
    int nA = nta - co;                        // qa tiles in this window
    nA = nA < 0 ? 0 : (nA > clen ? clen : nA);

    const float C1 = 0.18033688011112042f;    // 0.125 * log2(e)
    const float C2 = 12.262908856239697f;     // 8.5  * log2(e)

    // partial slots (all in d_ws overlay): A0,A1 rows [0,1024); B0,B1,B2 rows
    // [1024,2048). L slots (5 x 128K fp32) in d_out (tiny; proven in R4).
    unsigned short* OhA = OpW + (size_t)c * 1024 * DOUT;
    float*          LhA = Lp + (size_t)c * 1024 * NH;
    unsigned short* OhB = OpW + (size_t)(2 + c) * 1024 * DOUT;
    float*          LhB = Lp + (size_t)(2 + c) * 1024 * NH;

    int seg = (c < 2) ? 0 : 1;                // chunk 2 is always all-qb
    int s0 = seg == 0 ? s0a : s0b;

    // Q fragments (B-operand layout): lane holds Q[s0+sl][16*ksq + 8*hi + j]
    short8v qf[4];
#pragma unroll
    for (int ksq = 0; ksq < 4; ksq++)
        qf[ksq] = *(const short8v*)(qb + (size_t)(s0 + sl) * QKVN + h * HD +
                                    ksq * 16 + hi8);

    float16v O[2], Lacc;
#pragma unroll
    for (int df = 0; df < 2; df++)
#pragma unroll
        for (int r = 0; r < 16; r++) O[df][r] = 0.f;
#pragma unroll
    for (int r = 0; r < 16; r++) Lacc[r] = 0.f;

    short8v ones;
#pragma unroll
    for (int i = 0; i < 8; i++) ones[i] = (short)0x3F80;   // bf16 1.0

    // staging addresses
    const int kkey = tid >> 2, kch = tid & 3;     // K: 4 threads/key, 16 shorts
    const unsigned short* kg = kb + (size_t)kkey * QKVN + g * HD + kch * 16;
    const int kp = tid & 31, vdbb = tid >> 5;     // V: keys 2kp,2kp+1; dims vdbb*8..+8
    const unsigned short* vg0 = vb + (size_t)(2 * kp) * QKVN + g * HD + vdbb * 8;
    const unsigned short* vg1 = vg0 + QKVN;

    auto epi = [&](int sbase, unsigned short* Os, float* Ls, int roff) {
#pragma unroll
        for (int df = 0; df < 2; df++)
#pragma unroll
            for (int r = 0; r < 16; r++) {
                const int row = sbase + (r & 3) + 8 * (r >> 2) + 4 * hi - roff;
                Os[(size_t)row * DOUT + h * HD + df * 32 + sl] = f2h(O[df][r]);
            }
        if (sl == 0) {
#pragma unroll
            for (int r = 0; r < 16; r++) {
                const int row = sbase + (r & 3) + 8 * (r >> 2) + 4 * hi - roff;
                Ls[(size_t)row * NH + h] = Lacc[r];
            }
        }
    };
    auto zacc = [&]() {
#pragma unroll
        for (int df = 0; df < 2; df++)
#pragma unroll
            for (int r = 0; r < 16; r++) O[df][r] = 0.f;
#pragma unroll
        for (int r = 0; r < 16; r++) Lacc[r] = 0.f;
    };

    auto kt = [&](int jj) {                   // key-tile index for stream pos jj
        const int sj = co + jj;
        return (sj < nta) ? sj : (sj - nta);
    };

    ushort8v ka0, ka1, va0, va1;
    auto LOADREGS = [&](int it) {
        const size_t off = (size_t)it * 64 * QKVN;
        ka0 = *(const ushort8v*)(kg + off);
        ka1 = *(const ushort8v*)(kg + off + 8);
        va0 = *(const ushort8v*)(vg0 + off);
        va1 = *(const ushort8v*)(vg1 + off);
    };
    auto COMMIT = [&](int b) {
        unsigned short* kd = Ks[b] + kkey * KSTR + kch * 16;
        *(ushort8v*)kd = ka0;
        *(ushort8v*)(kd + 8) = ka1;
        union { ushort8v v; unsigned d[4]; } ua, ub;
        ua.v = va0; ub.v = va1;
        unsigned short* vd = Vt[b] + (size_t)(vdbb * 8) * KSTR + 2 * kp;
#pragma unroll
        for (int i = 0; i < 8; i++) {
            const unsigned sel = (i & 1) ? 0x07060302u : 0x05040100u;
            const unsigned word = __builtin_amdgcn_perm(ub.d[i >> 1], ua.d[i >> 1], sel);
            *(unsigned*)(vd + (size_t)i * KSTR) = word;
        }
    };

    // prologue: tile0 -> regs -> buf0; tile1 -> regs
    LOADREGS(kt(0));
    COMMIT(0);
    LOADREGS(kt(1));

#pragma unroll 1
    for (int jj = 0; jj < clen; jj++) {
        const int cur = jj & 1;
        __syncthreads();                    // buf[cur] committed; prev reads done
        if (jj + 1 < clen) COMMIT(cur ^ 1); // regs hold tile jj+1
        if (jj + 2 < clen) LOADREGS(kt(jj + 2));
        if (seg == 0 && jj == nA) {         // qa -> qb boundary
            if (nA) {                       // flush A partial only if non-empty
                epi(s0a, OhA, LhA, 0);
                zacc();
            }
            s0 = s0b; seg = 1;
#pragma unroll
            for (int ksq = 0; ksq < 4; ksq++)
                qf[ksq] = *(const short8v*)(qb + (size_t)(s0b + sl) * QKVN +
                                            h * HD + ksq * 16 + hi8);
        }

        const int t0 = kt(jj) * 64;
        const bool edge = (t0 + 63 > s0);

#pragma unroll
        for (int b = 0; b < 2; b++) {
            short8v kf[4];
#pragma unroll
            for (int ksq = 0; ksq < 4; ksq++)
                kf[ksq] = *(const short8v*)(Ks[cur] + (32 * b + sl) * KSTR +
                                            ksq * 16 + hi8);
            float16v sct;
#pragma unroll
            for (int r = 0; r < 16; r++) sct[r] = 0.f;
            __builtin_amdgcn_s_setprio(1);
#pragma unroll
            for (int ksq = 0; ksq < 4; ksq++)
                sct = __builtin_amdgcn_mfma_f32_32x32x16_bf16(kf[ksq], qf[ksq],
                                                              sct, 0, 0, 0);
            __builtin_amdgcn_s_setprio(0);
#pragma unroll
            for (int r = 0; r < 16; r++) {
                float arg = sct[r] * C1 - C2;
                if (edge) {
                    const int kglob = t0 + 32 * b + (r & 3) + 8 * (r >> 2) + 4 * hi;
                    arg = (kglob <= s0 + sl) ? arg : -100.f;
                }
                sct[r] = fexp2(arg);
            }
            unsigned pk[8];
#pragma unroll
            for (int i = 0; i < 8; i++) pk[i] = cvtpk(sct[2 * i], sct[2 * i + 1]);
#pragma unroll
            for (int kk = 0; kk < 2; kk++) {
                unsigned x0 = pk[4 * kk + 0], x1 = pk[4 * kk + 1];
                unsigned y0 = pk[4 * kk + 2], y1 = pk[4 * kk + 3];
                // halves swap: x' = {x_lo, y_lo}, y' = {x_hi, y_hi}
                asm("v_permlane32_swap_b32 %0, %1" : "+v"(x0), "+v"(y0));
                asm("v_permlane32_swap_b32 %0, %1" : "+v"(x1), "+v"(y1));
                union { unsigned u[4]; short8v v; } pa;
                pa.u[0] = x0; pa.u[1] = x1; pa.u[2] = y0; pa.u[3] = y1;
                const int ks = 2 * b + kk;
                __builtin_amdgcn_s_setprio(1);
#pragma unroll
                for (int df = 0; df < 2; df++) {
                    const short8v vf = *(const short8v*)(Vt[cur] +
                                                         (size_t)(df * 32 + sl) * KSTR +
                                                         ks * 16 + hi8);
                    O[df] = __builtin_amdgcn_mfma_f32_32x32x16_bf16(pa.v, vf,
                                                                    O[df], 0, 0, 0);
                }
                Lacc = __builtin_amdgcn_mfma_f32_32x32x16_bf16(pa.v, ones,
                                                               Lacc, 0, 0, 0);
                __builtin_amdgcn_s_setprio(0);
            }
        }
    }

    if (seg == 0) {            // chunk0 all-qa (p>=20): flush A, B0 SKIPPED
        epi(s0a, OhA, LhA, 0); // (combine: B0 invalid for rows < 1408)
    } else {
        epi(s0b, OhB, LhB, 1024);
    }
}

// ---------------------------------------------------------------------------
// Combine with validity masks (wave-uniform per block):
//   rows [0,704):      A0               rows [704,1024):  A0+A1
//   rows [1024,1408):  B1+B2            rows [1408,2048): B0+B1+B2
// ctx (bf16) written to CTX (the dead QKV region).
// ---------------------------------------------------------------------------
__global__ __launch_bounds__(256) void combine(const unsigned short* __restrict__ OpW,
                                               const float* __restrict__ Lp,
                                               unsigned short* __restrict__ CTX) {
    const int i4 = (blockIdx.x * 256 + threadIdx.x) * 4;
    const int row = i4 >> 11, hh = (i4 & 2047) >> 6;
    float acc[4];
    float l;
    if (row < 1024) {
        ushort4v a0 = *(const ushort4v*)(OpW + i4);
#pragma unroll
        for (int j = 0; j < 4; j++) acc[j] = h2f(a0[j]);
        l = Lp[(size_t)row * NH + hh];
        if (row >= 704) {                 // A1 valid (chunk1 had qa tiles)
            ushort4v a1 = *(const ushort4v*)(OpW + (size_t)1024 * DOUT + i4);
#pragma unroll
            for (int j = 0; j < 4; j++) acc[j] += h2f(a1[j]);
            l += Lp[(size_t)(1024 + row) * NH + hh];
        }
    } else {
        const size_t j4 = (size_t)(row - 1024) * DOUT + (i4 & 2047);
        ushort4v b1 = *(const ushort4v*)(OpW + (size_t)3 * 1024 * DOUT + j4);
        ushort4v b2 = *(const ushort4v*)(OpW + (size_t)4 * 1024 * DOUT + j4);
#pragma unroll
        for (int j = 0; j < 4; j++) acc[j] = h2f(b1[j]) + h2f(b2[j]);
        const size_t lr = (size_t)(row - 1024) * NH + hh;
        l = Lp[(size_t)3 * 1024 * NH + lr] + Lp[(size_t)4 * 1024 * NH + lr];
        if (row >= 1408) {                // B0 valid (chunk0 reached qb)
            ushort4v b0 = *(const ushort4v*)(OpW + (size_t)2 * 1024 * DOUT + j4);
#pragma unroll
            for (int j = 0; j < 4; j++) acc[j] += h2f(b0[j]);
            l += Lp[(size_t)2 * 1024 * NH + lr];
        }
    }
    const float inv = 1.0f / l;
    ushort4v r;
#pragma unroll
    for (int j = 0; j < 4; j++) r[j] = f2bf(acc[j] * inv);
    *(ushort4v*)(CTX + i4) = r;
}

// ---------------------------------------------------------------------------
extern "C" void kernel_launch(void* const* d_in, const int* in_sizes, int n_in,
                              void* d_out, int out_size, void* d_ws, size_t ws_size,
                              hipStream_t stream) {
    const float* x    = (const float*)d_in[0];
    const float* cosb = (const float*)d_in[2];
    const float* sinb = (const float*)d_in[3];
    const float* Wq   = (const float*)d_in[4];
    const float* Wk   = (const float*)d_in[5];
    const float* Wv   = (const float*)d_in[6];
    const float* Wo   = (const float*)d_in[7];
    const float* qw   = (const float*)d_in[8];
    const float* kw   = (const float*)d_in[9];
    float* out = (float*)d_out;

    // ws layout (41.9 MB):
    //   W1  [0, 12.58M)      qkv weights^T bf16   -- dead after gemm_qkv
    //   XB  [12.58, 20.97M)  x bf16               -- dead after gemm_qkv
    //   WoT [20.97, 29.36M)  Wo^T bf16            -- live until out-proj
    //   QKV [29.36, 41.94M)  q|k|v bf16           -- dead after flash
    // flash partials: A0,A1,B0,B1,B2 OVERLAY W1+XB (exactly 5 x 4.19M fp16).
    // L slots (5 x 128K fp32) live at the START of d_out (dead until
    // out-proj; combine runs before it). combine writes ctx bf16 into the
    // dead QKV region; out-proj reads it.
    unsigned short* W1  = (unsigned short*)d_ws;
    unsigned short* XB  = W1 + (size_t)QKVN * DIN;
    unsigned short* WoT = XB + (size_t)S_LEN * DIN;
    unsigned short* QKV = WoT + (size_t)DIN * DOUT;
    unsigned short* OpW = (unsigned short*)d_ws;
    float*          Lp  = (float*)d_out;
    unsigned short* CTX = QKV;

    dim3 blk256(256);

    prep<<<dim3(14336), blk256, 0, stream>>>(Wq, Wk, Wv, Wo, x, W1, WoT, XB);

    gemm64<1><<<dim3(QKVN / 64, S_LEN / 128), blk256, 0, stream>>>(
        XB, W1, QKV, S_LEN, QKVN, DIN, qw, kw, cosb, sinb);

    // 768 uniform blocks: 8 kv-heads x 32 qtile-pairs x 3 chunks (11 tiles)
    flash_part<<<dim3(NKV * 32 * 3), blk256, 0, stream>>>(
        QKV, QKV + KOFF, QKV + VOFF, OpW, Lp);

    combine<<<dim3(S_LEN * DOUT / 1024), blk256, 0, stream>>>(OpW, Lp, CTX);

    gemm64<0><<<dim3(DIN / 64, S_LEN / 128), blk256, 0, stream>>>(
        CTX, WoT, out, S_LEN, DIN, DOUT, nullptr, nullptr, nullptr, nullptr);
}